// Round 10
// baseline (401.238 us; speedup 1.0000x reference)
//
#include <hip/hip_runtime.h>
#include <hip/hip_bf16.h>
#include <stdint.h>

#define BATCH 8
#define CH    64
#define HH    256
#define WW    256
#define TW    32
#define TH    16
#define PW    34          // TW+2
#define PH    18          // TH+2
#define NPIX  (PH*PW)     // 612
#define WELEM 36864       // 9*64*64

typedef __attribute__((ext_vector_type(8))) short short8;
typedef __attribute__((ext_vector_type(4))) float float4v;

__device__ __forceinline__ int swz(int byte) {
    // 128B-row XOR swizzle — proven 0-conflict (rounds 0-8) for 16B fragment reads
    return byte ^ (((byte >> 7) & 7) << 4);
}

__device__ __forceinline__ unsigned short f2bf(float v) {
    __hip_bfloat16 h = __float2bfloat16(v);
    return *reinterpret_cast<unsigned short*>(&h);
}

// async global->LDS, 16B per lane; ZERO VGPR cost (no staged value in registers).
// CONTRACT (m104/m108): LDS dest = readfirstlane(base) + lane*16. Only call with
// full-wave or lane-0-anchored-prefix exec and per-lane-linear lds addresses.
__device__ __forceinline__ void gl16(const void* g, void* l) {
    __builtin_amdgcn_global_load_lds(
        (const __attribute__((address_space(1))) unsigned int*)g,
        (__attribute__((address_space(3))) unsigned int*)l, 16, 0, 0);
}

// ---------------- weight prep: f32 OIHW -> bf16 [kk][o][c] PRE-SWIZZLED ----------------
// Global layout equals the swizzled-LDS layout, so staging is a linear copy and
// MFMA reads keep using swz(). swz on byte 2e == index XOR (o&7)<<3 on c.
__global__ __launch_bounds__(1024)
void prep_weights(const float* __restrict__ w1, const float* __restrict__ w2,
                  unsigned short* __restrict__ w1p, unsigned short* __restrict__ w2p) {
    int tid = blockIdx.x * blockDim.x + threadIdx.x;
    if (tid >= 2 * WELEM) return;
    const float* src = (tid < WELEM) ? w1 : w2;
    unsigned short* dst = (tid < WELEM) ? w1p : w2p;
    int e = (tid < WELEM) ? tid : tid - WELEM;
    int c  = e & 63;
    int o  = (e >> 6) & 63;
    int kk = e >> 12;                 // 0..8
    int cs = c ^ ((o & 7) << 3);      // pre-swizzle
    dst[kk * 4096 + o * 64 + cs] = f2bf(src[o * 576 + c * 9 + kk]);
}

// ---------------- gmax prep: 3x3 maxpool of gate -> gmax image (scratch in `out`) ----------------
__global__ __launch_bounds__(1024)
void gmax_prep(const float* __restrict__ gate, float* __restrict__ gmax) {
    int p = blockIdx.x * 1024 + threadIdx.x;   // 524288 px
    int b = p >> 16, rem = p & 65535, y = rem >> 8, x = rem & 255;
    const float* gb = gate + (size_t)b * 65536;
    float m = 0.f;
    #pragma unroll
    for (int dy = -1; dy <= 1; ++dy)
        #pragma unroll
        for (int dx = -1; dx <= 1; ++dx) {
            int yy = y + dy, xx = x + dx;
            if ((unsigned)yy < HH && (unsigned)xx < WW)
                m = fmaxf(m, gb[yy * 256 + xx]);
        }
    gmax[p] = m;
}

// ---------------- transpose: x NCHW f32 -> xbf NHWC bf16 ----------------
__global__ __launch_bounds__(256)
void transpose_x(const float* __restrict__ x, unsigned short* __restrict__ xbf) {
    __shared__ unsigned short tile[64 * 66];
    const int t = threadIdx.x;
    const int bx = blockIdx.x;                 // 8192 = B(8) * H(256) * W/64(4)
    const int xt = bx & 3, y = (bx >> 2) & 255, b = bx >> 10;
    const int x0 = xt * 64;
    const float* xb = x + (size_t)b * (64 * 65536) + y * 256 + x0;
    #pragma unroll
    for (int it = 0; it < 4; ++it) {
        int idx = it * 256 + t;
        int c = idx >> 4, xi = (idx & 15) * 4;
        float4 v = *reinterpret_cast<const float4*>(xb + (size_t)c * 65536 + xi);
        ushort4 o;
        o.x = f2bf(v.x); o.y = f2bf(v.y); o.z = f2bf(v.z); o.w = f2bf(v.w);
        *reinterpret_cast<ushort4*>(&tile[c * 66 + xi]) = o;
    }
    __syncthreads();
    unsigned short* ob = xbf + ((size_t)(b * 65536 + y * 256 + x0)) * 64;
    #pragma unroll
    for (int it = 0; it < 2; ++it) {
        int idx = it * 256 + t;
        int pix = idx >> 3, cg = idx & 7;
        unsigned short tmp[8];
        #pragma unroll
        for (int j = 0; j < 8; ++j) tmp[j] = tile[(cg * 8 + j) * 66 + pix];
        *reinterpret_cast<uint4*>(ob + (size_t)pix * 64 + cg * 8) = *reinterpret_cast<uint4*>(tmp);
    }
}

// ---------------- conv1 (persistent-4, gl16 prefetch under epilogue): xbf -> h ----------------
__global__ __launch_bounds__(1024, 1)
void conv1_kernel(const unsigned short* __restrict__ xbf, const float* __restrict__ gmaxg,
                  const unsigned short* __restrict__ wp,
                  const float* __restrict__ scale1, const float* __restrict__ bias1,
                  unsigned short* __restrict__ h) {
    __shared__ __align__(16) unsigned short patch[NPIX * 64];  // 78336 B
    __shared__ __align__(16) unsigned short wlds[WELEM];       // 73728 B

    const int tid = threadIdx.x;
    const int bid = blockIdx.x;                // 256 blocks, 4 x-adjacent tiles each
    const int tile0 = bid * 4;
    const int txi0 = tile0 & 7, tyi = (tile0 >> 3) & 15, b = tile0 >> 7;
    const int xb0 = txi0 * TW, y0 = tyi * TH;

    char* pb = (char*)patch;
    char* wb = (char*)wlds;

    // stage weights once: linear async copy (global pre-swizzled)
    #pragma unroll
    for (int i = 0; i < 5; ++i) {
        int s = tid + i * 1024;
        if (s < WELEM / 8)
            gl16((const char*)wp + s * 16, wb + s * 16);
    }
    const unsigned short* hbase = xbf + (size_t)b * (65536 * 64);
    // stage first patch: branchless gl16 (clamped source, linear dest) — proven r8
    #pragma unroll
    for (int i = 0; i < 5; ++i) {
        int s = tid + i * 1024;
        if (s < NPIX * 8) {                    // prefix-safe guard only
            int p = s >> 3, j = s & 7;
            int row = p / PW, px = p - row * PW;
            int y = y0 - 1 + row, xg = xb0 - 1 + px;
            bool valid = (unsigned)y < HH && (unsigned)xg < WW;
            int cc = j ^ (p & 7);
            size_t goff = valid ? ((size_t)(y * 256 + xg) * 64 + cc * 8) : 0;
            gl16(hbase + goff, pb + s * 16);
        }
    }
    __syncthreads();                           // drains vmcnt: gl16 writes landed
    #pragma unroll
    for (int i = 0; i < 5; ++i) {              // zero OOB slots of first tile
        int s = tid + i * 1024;
        if (s < NPIX * 8) {
            int p = s >> 3;
            int row = p / PW, px = p - row * PW;
            int y = y0 - 1 + row, xg = xb0 - 1 + px;
            if (!((unsigned)y < HH && (unsigned)xg < WW))
                *reinterpret_cast<uint4*>(pb + s * 16) = make_uint4(0u, 0u, 0u, 0u);
        }
    }
    __syncthreads();

    const int w = tid >> 6, l = tid & 63;      // 16 waves, wave = output row
    const int l15 = l & 15, lq = l >> 4;
    float s1v[4], b1v[4];
    #pragma unroll
    for (int nt = 0; nt < 4; ++nt) {
        s1v[nt] = scale1[nt * 16 + l15];
        b1v[nt] = bias1[nt * 16 + l15];
    }
    const int y = y0 + w;
    const float* gm = gmaxg + (size_t)b * 65536 + y * 256;
    unsigned short* hb = h + ((size_t)b * 65536 + (size_t)y * 256) * 64;

    for (int it = 0; it < 4; ++it) {
        const int x0 = xb0 + it * TW;
        // -- compute (round-0/8 body): A = patch pixels, B = weights, m2n4 --
        float4v acc[2][4];
        #pragma unroll
        for (int m = 0; m < 2; ++m)
            #pragma unroll
            for (int n = 0; n < 4; ++n)
                acc[m][n] = (float4v){0.f, 0.f, 0.f, 0.f};

        #pragma unroll
        for (int kk = 0; kk < 9; ++kk) {
            const int ky = kk / 3, kx = kk - ky * 3;
            #pragma unroll
            for (int kc = 0; kc < 2; ++kc) {
                const int kbyte = kc * 64 + lq * 16;
                short8 a0 = *reinterpret_cast<const short8*>(pb + swz(((w + ky) * PW + l15 + kx) * 128 + kbyte));
                short8 a1 = *reinterpret_cast<const short8*>(pb + swz(((w + ky) * PW + 16 + l15 + kx) * 128 + kbyte));
                #pragma unroll
                for (int nt = 0; nt < 4; ++nt) {
                    short8 bf = *reinterpret_cast<const short8*>(wb + swz((kk * 64 + nt * 16 + l15) * 128 + kbyte));
                    acc[0][nt] = __builtin_amdgcn_mfma_f32_16x16x32_bf16(a0, bf, acc[0][nt], 0, 0, 0);
                    acc[1][nt] = __builtin_amdgcn_mfma_f32_16x16x32_bf16(a1, bf, acc[1][nt], 0, 0, 0);
                }
            }
        }
        __syncthreads();                       // all patch reads of tile `it` done

        // -- issue gl16 prefetch of tile it+1 (register-free; flies under epilogue) --
        if (it < 3) {
            const int nx0 = x0 + TW;
            #pragma unroll
            for (int i = 0; i < 5; ++i) {
                int s = tid + i * 1024;
                if (s < NPIX * 8) {
                    int p = s >> 3, j = s & 7;
                    int row = p / PW, px = p - row * PW;
                    int yy = y0 - 1 + row, xg = nx0 - 1 + px;
                    bool valid = (unsigned)yy < HH && (unsigned)xg < WW;
                    int cc = j ^ (p & 7);
                    size_t goff = valid ? ((size_t)(yy * 256 + xg) * 64 + cc * 8) : 0;
                    gl16(hbase + goff, pb + s * 16);
                }
            }
        }

        // -- epilogue: BN1 + ReLU + *gmax(global), store NHWC bf16 (no LDS) --
        #pragma unroll
        for (int m = 0; m < 2; ++m)
            #pragma unroll
            for (int r = 0; r < 4; ++r) {
                int px = m * 16 + lq * 4 + r;
                float g = gm[x0 + px];
                #pragma unroll
                for (int nt = 0; nt < 4; ++nt) {
                    float v = acc[m][nt][r] * s1v[nt] + b1v[nt];
                    v = fmaxf(v, 0.f) * g;
                    hb[(size_t)(x0 + px) * 64 + nt * 16 + l15] = f2bf(v);
                }
            }

        if (it < 3) {
            __syncthreads();                   // drains vmcnt: prefetched patch landed
            const int nx0 = x0 + TW;
            #pragma unroll
            for (int i = 0; i < 5; ++i) {      // zero OOB slots of tile it+1
                int s = tid + i * 1024;
                if (s < NPIX * 8) {
                    int p = s >> 3;
                    int row = p / PW, px = p - row * PW;
                    int yy = y0 - 1 + row, xg = nx0 - 1 + px;
                    if (!((unsigned)yy < HH && (unsigned)xg < WW))
                        *reinterpret_cast<uint4*>(pb + s * 16) = make_uint4(0u, 0u, 0u, 0u);
                }
            }
            __syncthreads();
        }
    }
}

// ---------------- conv1 fallback (ws too small): x NCHW f32 in-kernel; linear weight copy ----------------
__global__ __launch_bounds__(1024, 1)
void conv1_fallback(const float* __restrict__ x, const float* __restrict__ gate,
                    const unsigned short* __restrict__ wp,
                    const float* __restrict__ scale1, const float* __restrict__ bias1,
                    unsigned short* __restrict__ h) {
    __shared__ __align__(16) unsigned short patch[NPIX * 64];
    __shared__ __align__(16) unsigned short wlds[WELEM];
    __shared__ float gpatch[NPIX];
    __shared__ float gmax[TH * TW];

    const int tid = threadIdx.x;
    const int bx  = blockIdx.x;
    const int txi = bx & 7, tyi = (bx >> 3) & 15, b = bx >> 7;
    const int x0 = txi * TW, y0 = tyi * TH;

    char* pb = (char*)patch;
    char* wb = (char*)wlds;

    const float* xb = x + (size_t)b * (64 * 65536);
    for (int e = tid; e < NPIX * 64; e += 1024) {
        int c  = e / NPIX;
        int rp = e - c * NPIX;
        int row = rp / PW;
        int px  = rp - row * PW;
        int y = y0 - 1 + row, xg = x0 - 1 + px;
        float v = 0.f;
        if ((unsigned)y < HH && (unsigned)xg < WW)
            v = xb[(size_t)c * 65536 + y * 256 + xg];
        *reinterpret_cast<unsigned short*>(pb + swz(rp * 128 + c * 2)) = f2bf(v);
    }
    const float* gb = gate + (size_t)b * 65536;
    for (int e = tid; e < NPIX; e += 1024) {
        int row = e / PW, px = e - row * PW;
        int y = y0 - 1 + row, xg = x0 - 1 + px;
        gpatch[e] = ((unsigned)y < HH && (unsigned)xg < WW) ? gb[y * 256 + xg] : 0.f;
    }
    // weights are pre-swizzled in global: linear copy
    for (int s = tid; s < WELEM / 8; s += 1024) {
        *reinterpret_cast<uint4*>(wb + s * 16) =
            *reinterpret_cast<const uint4*>((const char*)wp + s * 16);
    }
    __syncthreads();

    if (tid < TH * TW) {
        int r = tid >> 5, px = tid & 31;
        float m = 0.f;
        #pragma unroll
        for (int dy = 0; dy < 3; ++dy)
            #pragma unroll
            for (int dx = 0; dx < 3; ++dx)
                m = fmaxf(m, gpatch[(r + dy) * PW + px + dx]);
        gmax[tid] = m;
    }
    __syncthreads();

    const int w = tid >> 6, l = tid & 63;
    const int l15 = l & 15, lq = l >> 4;

    float4v acc[2][4];
    #pragma unroll
    for (int m = 0; m < 2; ++m)
        #pragma unroll
        for (int n = 0; n < 4; ++n)
            acc[m][n] = (float4v){0.f, 0.f, 0.f, 0.f};

    #pragma unroll
    for (int kk = 0; kk < 9; ++kk) {
        const int ky = kk / 3, kx = kk - ky * 3;
        #pragma unroll
        for (int kc = 0; kc < 2; ++kc) {
            const int kbyte = kc * 64 + lq * 16;
            short8 a0 = *reinterpret_cast<const short8*>(pb + swz(((w + ky) * PW + l15 + kx) * 128 + kbyte));
            short8 a1 = *reinterpret_cast<const short8*>(pb + swz(((w + ky) * PW + 16 + l15 + kx) * 128 + kbyte));
            #pragma unroll
            for (int nt = 0; nt < 4; ++nt) {
                short8 bf = *reinterpret_cast<const short8*>(wb + swz((kk * 64 + nt * 16 + l15) * 128 + kbyte));
                acc[0][nt] = __builtin_amdgcn_mfma_f32_16x16x32_bf16(a0, bf, acc[0][nt], 0, 0, 0);
                acc[1][nt] = __builtin_amdgcn_mfma_f32_16x16x32_bf16(a1, bf, acc[1][nt], 0, 0, 0);
            }
        }
    }

    float s1v[4], b1v[4];
    #pragma unroll
    for (int nt = 0; nt < 4; ++nt) {
        s1v[nt] = scale1[nt * 16 + l15];
        b1v[nt] = bias1[nt * 16 + l15];
    }
    const int y = y0 + w;
    unsigned short* hb = h + ((size_t)b * 65536 + (size_t)y * 256) * 64;
    #pragma unroll
    for (int m = 0; m < 2; ++m)
        #pragma unroll
        for (int r = 0; r < 4; ++r) {
            int px = m * 16 + lq * 4 + r;
            float g = gmax[w * 32 + px];
            #pragma unroll
            for (int nt = 0; nt < 4; ++nt) {
                float v = acc[m][nt][r] * s1v[nt] + b1v[nt];
                v = fmaxf(v, 0.f) * g;
                hb[(size_t)(x0 + px) * 64 + nt * 16 + l15] = f2bf(v);
            }
        }
}

// ---------------- conv2 (persistent-4, gl16 prefetch under epilogue): h -> out + residual ----------------
__global__ __launch_bounds__(1024, 1)
void conv2_kernel(const unsigned short* __restrict__ h, const float* __restrict__ x,
                  const float* __restrict__ gate, const unsigned short* __restrict__ wp,
                  const float* __restrict__ scale2, const float* __restrict__ bias2,
                  float* __restrict__ out) {
    __shared__ __align__(16) unsigned short patch[NPIX * 64];
    __shared__ __align__(16) unsigned short wlds[WELEM];

    const int tid = threadIdx.x;
    const int bid = blockIdx.x;
    const int tile0 = bid * 4;
    const int txi0 = tile0 & 7, tyi = (tile0 >> 3) & 15, b = tile0 >> 7;
    const int xb0 = txi0 * TW, y0 = tyi * TH;

    char* pb = (char*)patch;
    char* wb = (char*)wlds;

    // stage weights once
    #pragma unroll
    for (int i = 0; i < 5; ++i) {
        int s = tid + i * 1024;
        if (s < WELEM / 8)
            gl16((const char*)wp + s * 16, wb + s * 16);
    }
    const unsigned short* hbase = h + (size_t)b * (65536 * 64);
    // stage first patch
    #pragma unroll
    for (int i = 0; i < 5; ++i) {
        int s = tid + i * 1024;
        if (s < NPIX * 8) {
            int p = s >> 3, j = s & 7;
            int row = p / PW, px = p - row * PW;
            int y = y0 - 1 + row, xg = xb0 - 1 + px;
            bool valid = (unsigned)y < HH && (unsigned)xg < WW;
            int cc = j ^ (p & 7);
            size_t goff = valid ? ((size_t)(y * 256 + xg) * 64 + cc * 8) : 0;
            gl16(hbase + goff, pb + s * 16);
        }
    }
    __syncthreads();
    #pragma unroll
    for (int i = 0; i < 5; ++i) {
        int s = tid + i * 1024;
        if (s < NPIX * 8) {
            int p = s >> 3;
            int row = p / PW, px = p - row * PW;
            int y = y0 - 1 + row, xg = xb0 - 1 + px;
            if (!((unsigned)y < HH && (unsigned)xg < WW))
                *reinterpret_cast<uint4*>(pb + s * 16) = make_uint4(0u, 0u, 0u, 0u);
        }
    }
    __syncthreads();

    const int w = tid >> 6, l = tid & 63;      // 16 waves, wave = output row
    const int l15 = l & 15, lq = l >> 4;
    const int y = y0 + w;
    const float* gr = gate + (size_t)b * 65536 + y * 256;

    for (int it = 0; it < 4; ++it) {
        const int x0 = xb0 + it * TW;
        // -- compute (round-0/8 body): A = weights (oc), B = patch pixels, m4n2 --
        float4v acc[4][2];
        #pragma unroll
        for (int m = 0; m < 4; ++m)
            #pragma unroll
            for (int n = 0; n < 2; ++n)
                acc[m][n] = (float4v){0.f, 0.f, 0.f, 0.f};

        #pragma unroll
        for (int kk = 0; kk < 9; ++kk) {
            const int ky = kk / 3, kx = kk - ky * 3;
            #pragma unroll
            for (int kc = 0; kc < 2; ++kc) {
                const int kbyte = kc * 64 + lq * 16;
                short8 bp0 = *reinterpret_cast<const short8*>(pb + swz(((w + ky) * PW + l15 + kx) * 128 + kbyte));
                short8 bp1 = *reinterpret_cast<const short8*>(pb + swz(((w + ky) * PW + 16 + l15 + kx) * 128 + kbyte));
                #pragma unroll
                for (int mt = 0; mt < 4; ++mt) {
                    short8 aw = *reinterpret_cast<const short8*>(wb + swz((kk * 64 + mt * 16 + l15) * 128 + kbyte));
                    acc[mt][0] = __builtin_amdgcn_mfma_f32_16x16x32_bf16(aw, bp0, acc[mt][0], 0, 0, 0);
                    acc[mt][1] = __builtin_amdgcn_mfma_f32_16x16x32_bf16(aw, bp1, acc[mt][1], 0, 0, 0);
                }
            }
        }
        __syncthreads();                       // all patch reads of tile `it` done

        // -- issue gl16 prefetch of tile it+1 (register-free) --
        if (it < 3) {
            const int nx0 = x0 + TW;
            #pragma unroll
            for (int i = 0; i < 5; ++i) {
                int s = tid + i * 1024;
                if (s < NPIX * 8) {
                    int p = s >> 3, j = s & 7;
                    int row = p / PW, px = p - row * PW;
                    int yy = y0 - 1 + row, xg = nx0 - 1 + px;
                    bool valid = (unsigned)yy < HH && (unsigned)xg < WW;
                    int cc = j ^ (p & 7);
                    size_t goff = valid ? ((size_t)(yy * 256 + xg) * 64 + cc * 8) : 0;
                    gl16(hbase + goff, pb + s * 16);
                }
            }
        }

        // -- epilogue: BN2 + *gate + residual + ReLU, store NCHW f32 (no LDS) --
        float g0 = gr[x0 + l15], g1 = gr[x0 + 16 + l15];
        #pragma unroll
        for (int mt = 0; mt < 4; ++mt)
            #pragma unroll
            for (int r = 0; r < 4; ++r) {
                int oc = mt * 16 + lq * 4 + r;
                float sc = scale2[oc], bi = bias2[oc];
                size_t base = ((size_t)(b * 64 + oc) * 256 + y) * 256 + x0;
                #pragma unroll
                for (int nt = 0; nt < 2; ++nt) {
                    int px = nt * 16 + l15;
                    float v = acc[mt][nt][r] * sc + bi;
                    v *= (nt ? g1 : g0);
                    v += x[base + px];
                    out[base + px] = fmaxf(v, 0.f);
                }
            }

        if (it < 3) {
            __syncthreads();                   // drains vmcnt: prefetched patch landed
            const int nx0 = x0 + TW;
            #pragma unroll
            for (int i = 0; i < 5; ++i) {
                int s = tid + i * 1024;
                if (s < NPIX * 8) {
                    int p = s >> 3;
                    int row = p / PW, px = p - row * PW;
                    int yy = y0 - 1 + row, xg = nx0 - 1 + px;
                    if (!((unsigned)yy < HH && (unsigned)xg < WW))
                        *reinterpret_cast<uint4*>(pb + s * 16) = make_uint4(0u, 0u, 0u, 0u);
                }
            }
            __syncthreads();
        }
    }
}

extern "C" void kernel_launch(void* const* d_in, const int* in_sizes, int n_in,
                              void* d_out, int out_size, void* d_ws, size_t ws_size,
                              hipStream_t stream) {
    const float* x      = (const float*)d_in[0];
    const float* gate   = (const float*)d_in[1];
    const float* w1     = (const float*)d_in[2];
    const float* scale1 = (const float*)d_in[3];
    const float* bias1  = (const float*)d_in[4];
    const float* w2     = (const float*)d_in[5];
    const float* scale2 = (const float*)d_in[6];
    const float* bias2  = (const float*)d_in[7];
    float* out = (float*)d_out;

    char* ws = (char*)d_ws;
    const size_t HBYTES = 67108864;            // 64 MiB NHWC bf16 h
    const size_t NEED_BIG = 2 * HBYTES + 2 * 73728;

    // gmax (3x3 maxpool of gate) lives in `out` as scratch: consumed only by conv1,
    // then conv2 fully overwrites out (stream-ordered). Proven rounds 5-8.
    float* gmaxbuf = out;

    if (ws_size >= NEED_BIG) {
        unsigned short* hbuf = (unsigned short*)ws;
        unsigned short* xbf  = (unsigned short*)(ws + HBYTES);
        unsigned short* w1p  = (unsigned short*)(ws + 2 * HBYTES);
        unsigned short* w2p  = (unsigned short*)(ws + 2 * HBYTES + 73728);
        prep_weights<<<72, 1024, 0, stream>>>(w1, w2, w1p, w2p);
        gmax_prep<<<512, 1024, 0, stream>>>(gate, gmaxbuf);
        transpose_x<<<8192, 256, 0, stream>>>(x, xbf);
        conv1_kernel<<<256, 1024, 0, stream>>>(xbf, gmaxbuf, w1p, scale1, bias1, hbuf);
        conv2_kernel<<<256, 1024, 0, stream>>>(hbuf, x, gate, w2p, scale2, bias2, out);
    } else {
        unsigned short* hbuf = (unsigned short*)ws;
        unsigned short* w1p  = (unsigned short*)(ws + HBYTES);
        unsigned short* w2p  = (unsigned short*)(ws + HBYTES + 73728);
        prep_weights<<<72, 1024, 0, stream>>>(w1, w2, w1p, w2p);
        conv1_fallback<<<1024, 1024, 0, stream>>>(x, gate, w1p, scale1, bias1, hbuf);
        conv2_kernel<<<256, 1024, 0, stream>>>(hbuf, x, gate, w2p, scale2, bias2, out);
    }
}

// Round 11
// 197.817 us; speedup vs baseline: 2.0283x; 2.0283x over previous
//
#include <hip/hip_runtime.h>
#include <hip/hip_bf16.h>
#include <stdint.h>

#define BATCH 8
#define CH    64
#define HH    256
#define WW    256
#define TW    32
#define TH    16
#define PW    34          // TW+2
#define PH    18          // TH+2
#define NPIX  (PH*PW)     // 612
#define WELEM 36864       // 9*64*64
// conv2 small-tile geometry (2 blocks/CU)
#define T2H   8
#define P2H   10
#define N2PIX (P2H*PW)    // 340

typedef __attribute__((ext_vector_type(8))) short short8;
typedef __attribute__((ext_vector_type(4))) float float4v;

__device__ __forceinline__ int swz(int byte) {
    // 128B-row XOR swizzle — proven 0-conflict (rounds 0-8) for 16B fragment reads
    return byte ^ (((byte >> 7) & 7) << 4);
}

__device__ __forceinline__ unsigned short f2bf(float v) {
    __hip_bfloat16 h = __float2bfloat16(v);
    return *reinterpret_cast<unsigned short*>(&h);
}

// async global->LDS, 16B per lane; zero VGPR cost.
// CONTRACT (m104/m108): LDS dest = readfirstlane(base) + lane*16. Only call with
// full-wave or lane-0-anchored-prefix exec and per-lane-linear lds addresses.
__device__ __forceinline__ void gl16(const void* g, void* l) {
    __builtin_amdgcn_global_load_lds(
        (const __attribute__((address_space(1))) unsigned int*)g,
        (__attribute__((address_space(3))) unsigned int*)l, 16, 0, 0);
}

// ---------------- weight prep: f32 OIHW -> bf16 [kk][o][c] PRE-SWIZZLED ----------------
__global__ __launch_bounds__(1024)
void prep_weights(const float* __restrict__ w1, const float* __restrict__ w2,
                  unsigned short* __restrict__ w1p, unsigned short* __restrict__ w2p) {
    int tid = blockIdx.x * blockDim.x + threadIdx.x;
    if (tid >= 2 * WELEM) return;
    const float* src = (tid < WELEM) ? w1 : w2;
    unsigned short* dst = (tid < WELEM) ? w1p : w2p;
    int e = (tid < WELEM) ? tid : tid - WELEM;
    int c  = e & 63;
    int o  = (e >> 6) & 63;
    int kk = e >> 12;                 // 0..8
    int cs = c ^ ((o & 7) << 3);      // pre-swizzle
    dst[kk * 4096 + o * 64 + cs] = f2bf(src[o * 576 + c * 9 + kk]);
}

// ---------------- gmax prep: 3x3 maxpool of gate -> gmax image (scratch in `out`) ----------------
__global__ __launch_bounds__(1024)
void gmax_prep(const float* __restrict__ gate, float* __restrict__ gmax) {
    int p = blockIdx.x * 1024 + threadIdx.x;   // 524288 px
    int b = p >> 16, rem = p & 65535, y = rem >> 8, x = rem & 255;
    const float* gb = gate + (size_t)b * 65536;
    float m = 0.f;
    #pragma unroll
    for (int dy = -1; dy <= 1; ++dy)
        #pragma unroll
        for (int dx = -1; dx <= 1; ++dx) {
            int yy = y + dy, xx = x + dx;
            if ((unsigned)yy < HH && (unsigned)xx < WW)
                m = fmaxf(m, gb[yy * 256 + xx]);
        }
    gmax[p] = m;
}

// ---------------- transpose: x NCHW f32 -> xbf NHWC bf16 ----------------
__global__ __launch_bounds__(256)
void transpose_x(const float* __restrict__ x, unsigned short* __restrict__ xbf) {
    __shared__ unsigned short tile[64 * 66];
    const int t = threadIdx.x;
    const int bx = blockIdx.x;                 // 8192 = B(8) * H(256) * W/64(4)
    const int xt = bx & 3, y = (bx >> 2) & 255, b = bx >> 10;
    const int x0 = xt * 64;
    const float* xb = x + (size_t)b * (64 * 65536) + y * 256 + x0;
    #pragma unroll
    for (int it = 0; it < 4; ++it) {
        int idx = it * 256 + t;
        int c = idx >> 4, xi = (idx & 15) * 4;
        float4 v = *reinterpret_cast<const float4*>(xb + (size_t)c * 65536 + xi);
        ushort4 o;
        o.x = f2bf(v.x); o.y = f2bf(v.y); o.z = f2bf(v.z); o.w = f2bf(v.w);
        *reinterpret_cast<ushort4*>(&tile[c * 66 + xi]) = o;
    }
    __syncthreads();
    unsigned short* ob = xbf + ((size_t)(b * 65536 + y * 256 + x0)) * 64;
    #pragma unroll
    for (int it = 0; it < 2; ++it) {
        int idx = it * 256 + t;
        int pix = idx >> 3, cg = idx & 7;
        unsigned short tmp[8];
        #pragma unroll
        for (int j = 0; j < 8; ++j) tmp[j] = tile[(cg * 8 + j) * 66 + pix];
        *reinterpret_cast<uint4*>(ob + (size_t)pix * 64 + cg * 8) = *reinterpret_cast<uint4*>(tmp);
    }
}

// ---------------- conv1 (round-8 champion, unchanged): xbf -> h ----------------
__global__ __launch_bounds__(1024, 1)
void conv1_kernel(const unsigned short* __restrict__ xbf, const float* __restrict__ gmaxg,
                  const unsigned short* __restrict__ wp,
                  const float* __restrict__ scale1, const float* __restrict__ bias1,
                  unsigned short* __restrict__ h) {
    __shared__ __align__(16) unsigned short patch[NPIX * 64];  // 78336 B
    __shared__ __align__(16) unsigned short wlds[WELEM];       // 73728 B

    const int tid = threadIdx.x;
    const int bx  = blockIdx.x;                // 1024 = 8 tx * 16 ty * 8 b
    const int txi = bx & 7, tyi = (bx >> 3) & 15, b = bx >> 7;
    const int x0 = txi * TW, y0 = tyi * TH;

    char* pb = (char*)patch;
    char* wb = (char*)wlds;

    #pragma unroll
    for (int i = 0; i < 5; ++i) {
        int s = tid + i * 1024;
        if (s < WELEM / 8)
            gl16((const char*)wp + s * 16, wb + s * 16);
    }
    const unsigned short* hbase = xbf + (size_t)b * (65536 * 64);
    #pragma unroll
    for (int i = 0; i < 5; ++i) {
        int s = tid + i * 1024;
        if (s < NPIX * 8) {
            int p = s >> 3, j = s & 7;
            int row = p / PW, px = p - row * PW;
            int y = y0 - 1 + row, xg = x0 - 1 + px;
            bool valid = (unsigned)y < HH && (unsigned)xg < WW;
            int cc = j ^ (p & 7);
            size_t goff = valid ? ((size_t)(y * 256 + xg) * 64 + cc * 8) : 0;
            gl16(hbase + goff, pb + s * 16);
        }
    }
    __syncthreads();
    #pragma unroll
    for (int i = 0; i < 5; ++i) {
        int s = tid + i * 1024;
        if (s < NPIX * 8) {
            int p = s >> 3;
            int row = p / PW, px = p - row * PW;
            int y = y0 - 1 + row, xg = x0 - 1 + px;
            if (!((unsigned)y < HH && (unsigned)xg < WW))
                *reinterpret_cast<uint4*>(pb + s * 16) = make_uint4(0u, 0u, 0u, 0u);
        }
    }
    __syncthreads();

    const int w = tid >> 6, l = tid & 63;
    const int l15 = l & 15, lq = l >> 4;

    float4v acc[2][4];
    #pragma unroll
    for (int m = 0; m < 2; ++m)
        #pragma unroll
        for (int n = 0; n < 4; ++n)
            acc[m][n] = (float4v){0.f, 0.f, 0.f, 0.f};

    #pragma unroll
    for (int kk = 0; kk < 9; ++kk) {
        const int ky = kk / 3, kx = kk - ky * 3;
        #pragma unroll
        for (int kc = 0; kc < 2; ++kc) {
            const int kbyte = kc * 64 + lq * 16;
            short8 a0 = *reinterpret_cast<const short8*>(pb + swz(((w + ky) * PW + l15 + kx) * 128 + kbyte));
            short8 a1 = *reinterpret_cast<const short8*>(pb + swz(((w + ky) * PW + 16 + l15 + kx) * 128 + kbyte));
            #pragma unroll
            for (int nt = 0; nt < 4; ++nt) {
                short8 bf = *reinterpret_cast<const short8*>(wb + swz((kk * 64 + nt * 16 + l15) * 128 + kbyte));
                acc[0][nt] = __builtin_amdgcn_mfma_f32_16x16x32_bf16(a0, bf, acc[0][nt], 0, 0, 0);
                acc[1][nt] = __builtin_amdgcn_mfma_f32_16x16x32_bf16(a1, bf, acc[1][nt], 0, 0, 0);
            }
        }
    }

    float s1v[4], b1v[4];
    #pragma unroll
    for (int nt = 0; nt < 4; ++nt) {
        s1v[nt] = scale1[nt * 16 + l15];
        b1v[nt] = bias1[nt * 16 + l15];
    }
    const int y = y0 + w;
    const float* gm = gmaxg + (size_t)b * 65536 + y * 256;
    unsigned short* hb = h + ((size_t)b * 65536 + (size_t)y * 256) * 64;
    #pragma unroll
    for (int m = 0; m < 2; ++m)
        #pragma unroll
        for (int r = 0; r < 4; ++r) {
            int px = m * 16 + lq * 4 + r;
            float g = gm[x0 + px];
            #pragma unroll
            for (int nt = 0; nt < 4; ++nt) {
                float v = acc[m][nt][r] * s1v[nt] + b1v[nt];
                v = fmaxf(v, 0.f) * g;
                hb[(size_t)(x0 + px) * 64 + nt * 16 + l15] = f2bf(v);
            }
        }
}

// ---------------- conv1 fallback (ws too small): round-8 version unchanged ----------------
__global__ __launch_bounds__(1024, 1)
void conv1_fallback(const float* __restrict__ x, const float* __restrict__ gate,
                    const unsigned short* __restrict__ wp,
                    const float* __restrict__ scale1, const float* __restrict__ bias1,
                    unsigned short* __restrict__ h) {
    __shared__ __align__(16) unsigned short patch[NPIX * 64];
    __shared__ __align__(16) unsigned short wlds[WELEM];
    __shared__ float gpatch[NPIX];
    __shared__ float gmax[TH * TW];

    const int tid = threadIdx.x;
    const int bx  = blockIdx.x;
    const int txi = bx & 7, tyi = (bx >> 3) & 15, b = bx >> 7;
    const int x0 = txi * TW, y0 = tyi * TH;

    char* pb = (char*)patch;
    char* wb = (char*)wlds;

    const float* xb = x + (size_t)b * (64 * 65536);
    for (int e = tid; e < NPIX * 64; e += 1024) {
        int c  = e / NPIX;
        int rp = e - c * NPIX;
        int row = rp / PW;
        int px  = rp - row * PW;
        int y = y0 - 1 + row, xg = x0 - 1 + px;
        float v = 0.f;
        if ((unsigned)y < HH && (unsigned)xg < WW)
            v = xb[(size_t)c * 65536 + y * 256 + xg];
        *reinterpret_cast<unsigned short*>(pb + swz(rp * 128 + c * 2)) = f2bf(v);
    }
    const float* gb = gate + (size_t)b * 65536;
    for (int e = tid; e < NPIX; e += 1024) {
        int row = e / PW, px = e - row * PW;
        int y = y0 - 1 + row, xg = x0 - 1 + px;
        gpatch[e] = ((unsigned)y < HH && (unsigned)xg < WW) ? gb[y * 256 + xg] : 0.f;
    }
    for (int s = tid; s < WELEM / 8; s += 1024) {
        *reinterpret_cast<uint4*>(wb + s * 16) =
            *reinterpret_cast<const uint4*>((const char*)wp + s * 16);
    }
    __syncthreads();

    if (tid < TH * TW) {
        int r = tid >> 5, px = tid & 31;
        float m = 0.f;
        #pragma unroll
        for (int dy = 0; dy < 3; ++dy)
            #pragma unroll
            for (int dx = 0; dx < 3; ++dx)
                m = fmaxf(m, gpatch[(r + dy) * PW + px + dx]);
        gmax[tid] = m;
    }
    __syncthreads();

    const int w = tid >> 6, l = tid & 63;
    const int l15 = l & 15, lq = l >> 4;

    float4v acc[2][4];
    #pragma unroll
    for (int m = 0; m < 2; ++m)
        #pragma unroll
        for (int n = 0; n < 4; ++n)
            acc[m][n] = (float4v){0.f, 0.f, 0.f, 0.f};

    #pragma unroll
    for (int kk = 0; kk < 9; ++kk) {
        const int ky = kk / 3, kx = kk - ky * 3;
        #pragma unroll
        for (int kc = 0; kc < 2; ++kc) {
            const int kbyte = kc * 64 + lq * 16;
            short8 a0 = *reinterpret_cast<const short8*>(pb + swz(((w + ky) * PW + l15 + kx) * 128 + kbyte));
            short8 a1 = *reinterpret_cast<const short8*>(pb + swz(((w + ky) * PW + 16 + l15 + kx) * 128 + kbyte));
            #pragma unroll
            for (int nt = 0; nt < 4; ++nt) {
                short8 bf = *reinterpret_cast<const short8*>(wb + swz((kk * 64 + nt * 16 + l15) * 128 + kbyte));
                acc[0][nt] = __builtin_amdgcn_mfma_f32_16x16x32_bf16(a0, bf, acc[0][nt], 0, 0, 0);
                acc[1][nt] = __builtin_amdgcn_mfma_f32_16x16x32_bf16(a1, bf, acc[1][nt], 0, 0, 0);
            }
        }
    }

    float s1v[4], b1v[4];
    #pragma unroll
    for (int nt = 0; nt < 4; ++nt) {
        s1v[nt] = scale1[nt * 16 + l15];
        b1v[nt] = bias1[nt * 16 + l15];
    }
    const int y = y0 + w;
    unsigned short* hb = h + ((size_t)b * 65536 + (size_t)y * 256) * 64;
    #pragma unroll
    for (int m = 0; m < 2; ++m)
        #pragma unroll
        for (int r = 0; r < 4; ++r) {
            int px = m * 16 + lq * 4 + r;
            float g = gmax[w * 32 + px];
            #pragma unroll
            for (int nt = 0; nt < 4; ++nt) {
                float v = acc[m][nt][r] * s1v[nt] + b1v[nt];
                v = fmaxf(v, 0.f) * g;
                hb[(size_t)(x0 + px) * 64 + nt * 16 + l15] = f2bf(v);
            }
        }
}

// ---------------- conv2: TH=8 tile, kk-chunked weights, 2 blocks/CU ----------------
__global__ __launch_bounds__(1024, 1)
void conv2_kernel(const unsigned short* __restrict__ h, const float* __restrict__ x,
                  const float* __restrict__ gate, const unsigned short* __restrict__ wp,
                  const float* __restrict__ scale2, const float* __restrict__ bias2,
                  float* __restrict__ out) {
    __shared__ __align__(16) unsigned short patch[N2PIX * 64];  // 43520 B
    __shared__ __align__(16) unsigned short wlds[4 * 64 * 64];  // 32768 B -> 76288 total

    const int tid = threadIdx.x;
    const int bx  = blockIdx.x;                // 2048 = 8 tx * 32 ty * 8 b
    const int txi = bx & 7, tyi = (bx >> 3) & 31, b = bx >> 8;
    const int x0 = txi * TW, y0 = tyi * T2H;

    char* pb = (char*)patch;
    char* wb = (char*)wlds;

    // stage weight chunk 0 (kk 0-3): 2048 gl16, exact 2/thread
    #pragma unroll
    for (int i = 0; i < 2; ++i) {
        int s = tid + i * 1024;
        gl16((const char*)wp + s * 16, wb + s * 16);
    }
    // stage h patch: branchless gl16 (clamped source, linear dest)
    const unsigned short* hbase = h + (size_t)b * (65536 * 64);
    #pragma unroll
    for (int i = 0; i < 3; ++i) {
        int s = tid + i * 1024;
        if (s < N2PIX * 8) {
            int p = s >> 3, j = s & 7;
            int row = p / PW, px = p - row * PW;
            int y = y0 - 1 + row, xg = x0 - 1 + px;
            bool valid = (unsigned)y < HH && (unsigned)xg < WW;
            int cc = j ^ (p & 7);
            size_t goff = valid ? ((size_t)(y * 256 + xg) * 64 + cc * 8) : 0;
            gl16(hbase + goff, pb + s * 16);
        }
    }
    __syncthreads();                           // drains vmcnt
    #pragma unroll
    for (int i = 0; i < 3; ++i) {              // zero OOB slots (borders only)
        int s = tid + i * 1024;
        if (s < N2PIX * 8) {
            int p = s >> 3;
            int row = p / PW, px = p - row * PW;
            int y = y0 - 1 + row, xg = x0 - 1 + px;
            if (!((unsigned)y < HH && (unsigned)xg < WW))
                *reinterpret_cast<uint4*>(pb + s * 16) = make_uint4(0u, 0u, 0u, 0u);
        }
    }
    __syncthreads();

    const int w = tid >> 6, l = tid & 63;      // 16 waves
    const int l15 = l & 15, lq = l >> 4;
    const int rw = w >> 1;                     // output row 0..7
    const int oh = (w & 1) * 32;               // oc-half offset

    float4v acc[2][2];                         // [aw-frag][bp-half] = 16 VGPR
    #pragma unroll
    for (int m = 0; m < 2; ++m)
        #pragma unroll
        for (int n = 0; n < 2; ++n)
            acc[m][n] = (float4v){0.f, 0.f, 0.f, 0.f};

    #pragma unroll
    for (int ck = 0; ck < 3; ++ck) {           // weight chunks: kk {0-3},{4-7},{8}
        if (ck > 0) {
            __syncthreads();                   // all reads of prior chunk done
            const char* wsrc = (const char*)wp + ck * 32768;
            const int cnt = (ck == 2) ? 512 : 2048;
            #pragma unroll
            for (int i = 0; i < 2; ++i) {
                int s = tid + i * 1024;
                if (s < cnt)
                    gl16(wsrc + s * 16, wb + s * 16);
            }
            __syncthreads();                   // chunk visible (vmcnt drained)
        }
        const int kkn = (ck == 2) ? 1 : 4;
        #pragma unroll
        for (int kkl = 0; kkl < 4; ++kkl) {
            if (kkl < kkn) {
                const int kk = ck * 4 + kkl;
                const int ky = kk / 3, kx = kk - ky * 3;
                #pragma unroll
                for (int kc = 0; kc < 2; ++kc) {
                    const int kbyte = kc * 64 + lq * 16;
                    short8 bp0 = *reinterpret_cast<const short8*>(
                        pb + swz(((rw + ky) * PW + l15 + kx) * 128 + kbyte));
                    short8 bp1 = *reinterpret_cast<const short8*>(
                        pb + swz(((rw + ky) * PW + 16 + l15 + kx) * 128 + kbyte));
                    short8 aw0 = *reinterpret_cast<const short8*>(
                        wb + swz((kkl * 64 + oh + l15) * 128 + kbyte));
                    short8 aw1 = *reinterpret_cast<const short8*>(
                        wb + swz((kkl * 64 + oh + 16 + l15) * 128 + kbyte));
                    acc[0][0] = __builtin_amdgcn_mfma_f32_16x16x32_bf16(aw0, bp0, acc[0][0], 0, 0, 0);
                    acc[0][1] = __builtin_amdgcn_mfma_f32_16x16x32_bf16(aw0, bp1, acc[0][1], 0, 0, 0);
                    acc[1][0] = __builtin_amdgcn_mfma_f32_16x16x32_bf16(aw1, bp0, acc[1][0], 0, 0, 0);
                    acc[1][1] = __builtin_amdgcn_mfma_f32_16x16x32_bf16(aw1, bp1, acc[1][1], 0, 0, 0);
                }
            }
        }
    }

    // epilogue: BN2 + *gate + residual + ReLU, store NCHW f32 (coalesced: l15 = px)
    const int y = y0 + rw;
    const float* gr = gate + (size_t)b * 65536 + y * 256 + x0;
    float g0 = gr[l15], g1 = gr[16 + l15];
    #pragma unroll
    for (int a = 0; a < 2; ++a)
        #pragma unroll
        for (int r = 0; r < 4; ++r) {
            int oc = oh + a * 16 + lq * 4 + r;
            float sc = scale2[oc], bi = bias2[oc];
            size_t base = ((size_t)(b * 64 + oc) * 256 + y) * 256 + x0;
            #pragma unroll
            for (int p = 0; p < 2; ++p) {
                int px = p * 16 + l15;
                float v = acc[a][p][r] * sc + bi;
                v *= (p ? g1 : g0);
                v += x[base + px];
                out[base + px] = fmaxf(v, 0.f);
            }
        }
}

extern "C" void kernel_launch(void* const* d_in, const int* in_sizes, int n_in,
                              void* d_out, int out_size, void* d_ws, size_t ws_size,
                              hipStream_t stream) {
    const float* x      = (const float*)d_in[0];
    const float* gate   = (const float*)d_in[1];
    const float* w1     = (const float*)d_in[2];
    const float* scale1 = (const float*)d_in[3];
    const float* bias1  = (const float*)d_in[4];
    const float* w2     = (const float*)d_in[5];
    const float* scale2 = (const float*)d_in[6];
    const float* bias2  = (const float*)d_in[7];
    float* out = (float*)d_out;

    char* ws = (char*)d_ws;
    const size_t HBYTES = 67108864;            // 64 MiB NHWC bf16 h
    const size_t NEED_BIG = 2 * HBYTES + 2 * 73728;

    // gmax (3x3 maxpool of gate) lives in `out` as scratch (proven rounds 5-8).
    float* gmaxbuf = out;

    if (ws_size >= NEED_BIG) {
        unsigned short* hbuf = (unsigned short*)ws;
        unsigned short* xbf  = (unsigned short*)(ws + HBYTES);
        unsigned short* w1p  = (unsigned short*)(ws + 2 * HBYTES);
        unsigned short* w2p  = (unsigned short*)(ws + 2 * HBYTES + 73728);
        prep_weights<<<72, 1024, 0, stream>>>(w1, w2, w1p, w2p);
        gmax_prep<<<512, 1024, 0, stream>>>(gate, gmaxbuf);
        transpose_x<<<8192, 256, 0, stream>>>(x, xbf);
        conv1_kernel<<<1024, 1024, 0, stream>>>(xbf, gmaxbuf, w1p, scale1, bias1, hbuf);
        conv2_kernel<<<2048, 1024, 0, stream>>>(hbuf, x, gate, w2p, scale2, bias2, out);
    } else {
        unsigned short* hbuf = (unsigned short*)ws;
        unsigned short* w1p  = (unsigned short*)(ws + HBYTES);
        unsigned short* w2p  = (unsigned short*)(ws + HBYTES + 73728);
        prep_weights<<<72, 1024, 0, stream>>>(w1, w2, w1p, w2p);
        conv1_fallback<<<1024, 1024, 0, stream>>>(x, gate, w1p, scale1, bias1, hbuf);
        conv2_kernel<<<2048, 1024, 0, stream>>>(hbuf, x, gate, w2p, scale2, bias2, out);
    }
}

// Round 12
// 157.282 us; speedup vs baseline: 2.5511x; 1.2577x over previous
//
#include <hip/hip_runtime.h>
#include <hip/hip_bf16.h>
#include <stdint.h>

#define BATCH 8
#define CH    64
#define HH    256
#define WW    256
#define TW    32
#define TH    16
#define PW    34          // TW+2
#define PH    18          // TH+2
#define NPIX  (PH*PW)     // 612
#define WELEM 36864       // 9*64*64

typedef __attribute__((ext_vector_type(8))) short short8;
typedef __attribute__((ext_vector_type(4))) float float4v;

__device__ __forceinline__ int swz(int byte) {
    // 128B-row XOR swizzle — proven 0-conflict (rounds 0-11) for 16B fragment reads
    return byte ^ (((byte >> 7) & 7) << 4);
}

__device__ __forceinline__ unsigned short f2bf(float v) {
    __hip_bfloat16 h = __float2bfloat16(v);
    return *reinterpret_cast<unsigned short*>(&h);
}

__device__ __forceinline__ float bf2f(unsigned short u) {
    unsigned int x = ((unsigned int)u) << 16;
    return *reinterpret_cast<float*>(&x);
}

// async global->LDS, 16B per lane; zero VGPR cost.
// CONTRACT (m104/m108): LDS dest = readfirstlane(base) + lane*16. Only call with
// full-wave or lane-0-anchored-prefix exec and per-lane-linear lds addresses.
__device__ __forceinline__ void gl16(const void* g, void* l) {
    __builtin_amdgcn_global_load_lds(
        (const __attribute__((address_space(1))) unsigned int*)g,
        (__attribute__((address_space(3))) unsigned int*)l, 16, 0, 0);
}

// ---------------- fused prep: weights + gmax + transpose in ONE launch ----------------
// blocks [0,72):    weight prep  f32 OIHW -> bf16 [kk][o][c] PRE-SWIZZLED
// blocks [72,584):  gmax 3x3 maxpool of gate -> gmax image (scratch in `out`)
// blocks [584,2632): transpose x NCHW f32 -> xbf NHWC bf16 (4 tiles per block)
__global__ __launch_bounds__(1024)
void prep_all(const float* __restrict__ w1, const float* __restrict__ w2,
              const float* __restrict__ x, const float* __restrict__ gate,
              unsigned short* __restrict__ w1p, unsigned short* __restrict__ w2p,
              unsigned short* __restrict__ xbf, float* __restrict__ gmax) {
    __shared__ unsigned short tile[4][64 * 66];   // 33792 B (transpose section only)
    const int bx = blockIdx.x, t = threadIdx.x;

    if (bx < 72) {                                 // ---- weight prep ----
        int tid = bx * 1024 + t;
        if (tid < 2 * WELEM) {
            const float* src = (tid < WELEM) ? w1 : w2;
            unsigned short* dst = (tid < WELEM) ? w1p : w2p;
            int e = (tid < WELEM) ? tid : tid - WELEM;
            int c  = e & 63;
            int o  = (e >> 6) & 63;
            int kk = e >> 12;                      // 0..8
            int cs = c ^ ((o & 7) << 3);           // pre-swizzle
            dst[kk * 4096 + o * 64 + cs] = f2bf(src[o * 576 + c * 9 + kk]);
        }
        return;
    }
    if (bx < 584) {                                // ---- gmax ----
        int p = (bx - 72) * 1024 + t;              // 524288 px
        int b = p >> 16, rem = p & 65535, y = rem >> 8, xx0 = rem & 255;
        const float* gb = gate + (size_t)b * 65536;
        float m = 0.f;
        #pragma unroll
        for (int dy = -1; dy <= 1; ++dy)
            #pragma unroll
            for (int dx = -1; dx <= 1; ++dx) {
                int yy = y + dy, xx = xx0 + dx;
                if ((unsigned)yy < HH && (unsigned)xx < WW)
                    m = fmaxf(m, gb[yy * 256 + xx]);
            }
        gmax[p] = m;
        return;
    }
    // ---- transpose: 2048 blocks, 4 sub-tiles each (original 256-thread logic) ----
    const int sub = t >> 8, tt = t & 255;
    const int obx = (bx - 584) * 4 + sub;          // 0..8191
    const int xt = obx & 3, y = (obx >> 2) & 255, b = obx >> 10;
    const int x0 = xt * 64;
    const float* xb = x + (size_t)b * (64 * 65536) + y * 256 + x0;
    unsigned short* tl = tile[sub];
    #pragma unroll
    for (int it = 0; it < 4; ++it) {
        int idx = it * 256 + tt;
        int c = idx >> 4, xi = (idx & 15) * 4;
        float4 v = *reinterpret_cast<const float4*>(xb + (size_t)c * 65536 + xi);
        ushort4 o;
        o.x = f2bf(v.x); o.y = f2bf(v.y); o.z = f2bf(v.z); o.w = f2bf(v.w);
        *reinterpret_cast<ushort4*>(&tl[c * 66 + xi]) = o;
    }
    __syncthreads();                               // all 4 sub-tiles in same phase
    unsigned short* ob = xbf + ((size_t)(b * 65536 + y * 256 + x0)) * 64;
    #pragma unroll
    for (int it = 0; it < 2; ++it) {
        int idx = it * 256 + tt;
        int pix = idx >> 3, cg = idx & 7;
        unsigned short tmp[8];
        #pragma unroll
        for (int j = 0; j < 8; ++j) tmp[j] = tl[(cg * 8 + j) * 66 + pix];
        *reinterpret_cast<uint4*>(ob + (size_t)pix * 64 + cg * 8) = *reinterpret_cast<uint4*>(tmp);
    }
}

// ---------------- conv1 (round-8 champion, unchanged): xbf -> h ----------------
__global__ __launch_bounds__(1024, 1)
void conv1_kernel(const unsigned short* __restrict__ xbf, const float* __restrict__ gmaxg,
                  const unsigned short* __restrict__ wp,
                  const float* __restrict__ scale1, const float* __restrict__ bias1,
                  unsigned short* __restrict__ h) {
    __shared__ __align__(16) unsigned short patch[NPIX * 64];  // 78336 B
    __shared__ __align__(16) unsigned short wlds[WELEM];       // 73728 B

    const int tid = threadIdx.x;
    const int bx  = blockIdx.x;                // 1024 = 8 tx * 16 ty * 8 b
    const int txi = bx & 7, tyi = (bx >> 3) & 15, b = bx >> 7;
    const int x0 = txi * TW, y0 = tyi * TH;

    char* pb = (char*)patch;
    char* wb = (char*)wlds;

    #pragma unroll
    for (int i = 0; i < 5; ++i) {
        int s = tid + i * 1024;
        if (s < WELEM / 8)
            gl16((const char*)wp + s * 16, wb + s * 16);
    }
    const unsigned short* hbase = xbf + (size_t)b * (65536 * 64);
    #pragma unroll
    for (int i = 0; i < 5; ++i) {
        int s = tid + i * 1024;
        if (s < NPIX * 8) {
            int p = s >> 3, j = s & 7;
            int row = p / PW, px = p - row * PW;
            int y = y0 - 1 + row, xg = x0 - 1 + px;
            bool valid = (unsigned)y < HH && (unsigned)xg < WW;
            int cc = j ^ (p & 7);
            size_t goff = valid ? ((size_t)(y * 256 + xg) * 64 + cc * 8) : 0;
            gl16(hbase + goff, pb + s * 16);
        }
    }
    __syncthreads();
    #pragma unroll
    for (int i = 0; i < 5; ++i) {
        int s = tid + i * 1024;
        if (s < NPIX * 8) {
            int p = s >> 3;
            int row = p / PW, px = p - row * PW;
            int y = y0 - 1 + row, xg = x0 - 1 + px;
            if (!((unsigned)y < HH && (unsigned)xg < WW))
                *reinterpret_cast<uint4*>(pb + s * 16) = make_uint4(0u, 0u, 0u, 0u);
        }
    }
    __syncthreads();

    const int w = tid >> 6, l = tid & 63;
    const int l15 = l & 15, lq = l >> 4;

    float4v acc[2][4];
    #pragma unroll
    for (int m = 0; m < 2; ++m)
        #pragma unroll
        for (int n = 0; n < 4; ++n)
            acc[m][n] = (float4v){0.f, 0.f, 0.f, 0.f};

    #pragma unroll
    for (int kk = 0; kk < 9; ++kk) {
        const int ky = kk / 3, kx = kk - ky * 3;
        #pragma unroll
        for (int kc = 0; kc < 2; ++kc) {
            const int kbyte = kc * 64 + lq * 16;
            short8 a0 = *reinterpret_cast<const short8*>(pb + swz(((w + ky) * PW + l15 + kx) * 128 + kbyte));
            short8 a1 = *reinterpret_cast<const short8*>(pb + swz(((w + ky) * PW + 16 + l15 + kx) * 128 + kbyte));
            #pragma unroll
            for (int nt = 0; nt < 4; ++nt) {
                short8 bf = *reinterpret_cast<const short8*>(wb + swz((kk * 64 + nt * 16 + l15) * 128 + kbyte));
                acc[0][nt] = __builtin_amdgcn_mfma_f32_16x16x32_bf16(a0, bf, acc[0][nt], 0, 0, 0);
                acc[1][nt] = __builtin_amdgcn_mfma_f32_16x16x32_bf16(a1, bf, acc[1][nt], 0, 0, 0);
            }
        }
    }

    float s1v[4], b1v[4];
    #pragma unroll
    for (int nt = 0; nt < 4; ++nt) {
        s1v[nt] = scale1[nt * 16 + l15];
        b1v[nt] = bias1[nt * 16 + l15];
    }
    const int y = y0 + w;
    const float* gm = gmaxg + (size_t)b * 65536 + y * 256;
    unsigned short* hb = h + ((size_t)b * 65536 + (size_t)y * 256) * 64;
    #pragma unroll
    for (int m = 0; m < 2; ++m)
        #pragma unroll
        for (int r = 0; r < 4; ++r) {
            int px = m * 16 + lq * 4 + r;
            float g = gm[x0 + px];
            #pragma unroll
            for (int nt = 0; nt < 4; ++nt) {
                float v = acc[m][nt][r] * s1v[nt] + b1v[nt];
                v = fmaxf(v, 0.f) * g;
                hb[(size_t)(x0 + px) * 64 + nt * 16 + l15] = f2bf(v);
            }
        }
}

// ---------------- conv1 fallback (ws too small): round-8 version unchanged ----------------
__global__ __launch_bounds__(1024, 1)
void conv1_fallback(const float* __restrict__ x, const float* __restrict__ gate,
                    const unsigned short* __restrict__ wp,
                    const float* __restrict__ scale1, const float* __restrict__ bias1,
                    unsigned short* __restrict__ h) {
    __shared__ __align__(16) unsigned short patch[NPIX * 64];
    __shared__ __align__(16) unsigned short wlds[WELEM];
    __shared__ float gpatch[NPIX];
    __shared__ float gmax[TH * TW];

    const int tid = threadIdx.x;
    const int bx  = blockIdx.x;
    const int txi = bx & 7, tyi = (bx >> 3) & 15, b = bx >> 7;
    const int x0 = txi * TW, y0 = tyi * TH;

    char* pb = (char*)patch;
    char* wb = (char*)wlds;

    const float* xb = x + (size_t)b * (64 * 65536);
    for (int e = tid; e < NPIX * 64; e += 1024) {
        int c  = e / NPIX;
        int rp = e - c * NPIX;
        int row = rp / PW;
        int px  = rp - row * PW;
        int y = y0 - 1 + row, xg = x0 - 1 + px;
        float v = 0.f;
        if ((unsigned)y < HH && (unsigned)xg < WW)
            v = xb[(size_t)c * 65536 + y * 256 + xg];
        *reinterpret_cast<unsigned short*>(pb + swz(rp * 128 + c * 2)) = f2bf(v);
    }
    const float* gb = gate + (size_t)b * 65536;
    for (int e = tid; e < NPIX; e += 1024) {
        int row = e / PW, px = e - row * PW;
        int y = y0 - 1 + row, xg = x0 - 1 + px;
        gpatch[e] = ((unsigned)y < HH && (unsigned)xg < WW) ? gb[y * 256 + xg] : 0.f;
    }
    for (int s = tid; s < WELEM / 8; s += 1024) {
        *reinterpret_cast<uint4*>(wb + s * 16) =
            *reinterpret_cast<const uint4*>((const char*)wp + s * 16);
    }
    __syncthreads();

    if (tid < TH * TW) {
        int r = tid >> 5, px = tid & 31;
        float m = 0.f;
        #pragma unroll
        for (int dy = 0; dy < 3; ++dy)
            #pragma unroll
            for (int dx = 0; dx < 3; ++dx)
                m = fmaxf(m, gpatch[(r + dy) * PW + px + dx]);
        gmax[tid] = m;
    }
    __syncthreads();

    const int w = tid >> 6, l = tid & 63;
    const int l15 = l & 15, lq = l >> 4;

    float4v acc[2][4];
    #pragma unroll
    for (int m = 0; m < 2; ++m)
        #pragma unroll
        for (int n = 0; n < 4; ++n)
            acc[m][n] = (float4v){0.f, 0.f, 0.f, 0.f};

    #pragma unroll
    for (int kk = 0; kk < 9; ++kk) {
        const int ky = kk / 3, kx = kk - ky * 3;
        #pragma unroll
        for (int kc = 0; kc < 2; ++kc) {
            const int kbyte = kc * 64 + lq * 16;
            short8 a0 = *reinterpret_cast<const short8*>(pb + swz(((w + ky) * PW + l15 + kx) * 128 + kbyte));
            short8 a1 = *reinterpret_cast<const short8*>(pb + swz(((w + ky) * PW + 16 + l15 + kx) * 128 + kbyte));
            #pragma unroll
            for (int nt = 0; nt < 4; ++nt) {
                short8 bf = *reinterpret_cast<const short8*>(wb + swz((kk * 64 + nt * 16 + l15) * 128 + kbyte));
                acc[0][nt] = __builtin_amdgcn_mfma_f32_16x16x32_bf16(a0, bf, acc[0][nt], 0, 0, 0);
                acc[1][nt] = __builtin_amdgcn_mfma_f32_16x16x32_bf16(a1, bf, acc[1][nt], 0, 0, 0);
            }
        }
    }

    float s1v[4], b1v[4];
    #pragma unroll
    for (int nt = 0; nt < 4; ++nt) {
        s1v[nt] = scale1[nt * 16 + l15];
        b1v[nt] = bias1[nt * 16 + l15];
    }
    const int y = y0 + w;
    unsigned short* hb = h + ((size_t)b * 65536 + (size_t)y * 256) * 64;
    #pragma unroll
    for (int m = 0; m < 2; ++m)
        #pragma unroll
        for (int r = 0; r < 4; ++r) {
            int px = m * 16 + lq * 4 + r;
            float g = gmax[w * 32 + px];
            #pragma unroll
            for (int nt = 0; nt < 4; ++nt) {
                float v = acc[m][nt][r] * s1v[nt] + b1v[nt];
                v = fmaxf(v, 0.f) * g;
                hb[(size_t)(x0 + px) * 64 + nt * 16 + l15] = f2bf(v);
            }
        }
}

// ---------------- conv2 (round-8 body; residual from xbf bf16 when available) ----------------
__global__ __launch_bounds__(1024, 1)
void conv2_kernel(const unsigned short* __restrict__ h, const float* __restrict__ x,
                  const unsigned short* __restrict__ xr16,
                  const float* __restrict__ gate, const unsigned short* __restrict__ wp,
                  const float* __restrict__ scale2, const float* __restrict__ bias2,
                  float* __restrict__ out) {
    __shared__ __align__(16) unsigned short patch[NPIX * 64];
    __shared__ __align__(16) unsigned short wlds[WELEM];

    const int tid = threadIdx.x;
    const int bx  = blockIdx.x;
    const int txi = bx & 7, tyi = (bx >> 3) & 15, b = bx >> 7;
    const int x0 = txi * TW, y0 = tyi * TH;

    char* pb = (char*)patch;
    char* wb = (char*)wlds;

    #pragma unroll
    for (int i = 0; i < 5; ++i) {
        int s = tid + i * 1024;
        if (s < WELEM / 8)
            gl16((const char*)wp + s * 16, wb + s * 16);
    }
    const unsigned short* hbase = h + (size_t)b * (65536 * 64);
    #pragma unroll
    for (int i = 0; i < 5; ++i) {
        int s = tid + i * 1024;
        if (s < NPIX * 8) {
            int p = s >> 3, j = s & 7;
            int row = p / PW, px = p - row * PW;
            int y = y0 - 1 + row, xg = x0 - 1 + px;
            bool valid = (unsigned)y < HH && (unsigned)xg < WW;
            int cc = j ^ (p & 7);
            size_t goff = valid ? ((size_t)(y * 256 + xg) * 64 + cc * 8) : 0;
            gl16(hbase + goff, pb + s * 16);
        }
    }
    __syncthreads();
    #pragma unroll
    for (int i = 0; i < 5; ++i) {
        int s = tid + i * 1024;
        if (s < NPIX * 8) {
            int p = s >> 3;
            int row = p / PW, px = p - row * PW;
            int y = y0 - 1 + row, xg = x0 - 1 + px;
            if (!((unsigned)y < HH && (unsigned)xg < WW))
                *reinterpret_cast<uint4*>(pb + s * 16) = make_uint4(0u, 0u, 0u, 0u);
        }
    }
    __syncthreads();

    const int w = tid >> 6, l = tid & 63;      // 16 waves, wave = output row
    const int l15 = l & 15, lq = l >> 4;

    float4v acc[4][2];                         // [oc-frag][px-half]
    #pragma unroll
    for (int m = 0; m < 4; ++m)
        #pragma unroll
        for (int n = 0; n < 2; ++n)
            acc[m][n] = (float4v){0.f, 0.f, 0.f, 0.f};

    #pragma unroll
    for (int kk = 0; kk < 9; ++kk) {
        const int ky = kk / 3, kx = kk - ky * 3;
        #pragma unroll
        for (int kc = 0; kc < 2; ++kc) {
            const int kbyte = kc * 64 + lq * 16;
            short8 bp0 = *reinterpret_cast<const short8*>(pb + swz(((w + ky) * PW + l15 + kx) * 128 + kbyte));
            short8 bp1 = *reinterpret_cast<const short8*>(pb + swz(((w + ky) * PW + 16 + l15 + kx) * 128 + kbyte));
            #pragma unroll
            for (int mt = 0; mt < 4; ++mt) {
                short8 aw = *reinterpret_cast<const short8*>(wb + swz((kk * 64 + mt * 16 + l15) * 128 + kbyte));
                acc[mt][0] = __builtin_amdgcn_mfma_f32_16x16x32_bf16(aw, bp0, acc[mt][0], 0, 0, 0);
                acc[mt][1] = __builtin_amdgcn_mfma_f32_16x16x32_bf16(aw, bp1, acc[mt][1], 0, 0, 0);
            }
        }
    }

    // epilogue: BN2 + *gate + residual + ReLU, store NCHW f32 (coalesced: l15 = px)
    const int y = y0 + w;
    const float* gr = gate + (size_t)b * 65536 + y * 256 + x0;
    float g0 = gr[l15], g1 = gr[16 + l15];
    #pragma unroll
    for (int mt = 0; mt < 4; ++mt) {
        float sc4[4], bi4[4];
        #pragma unroll
        for (int r = 0; r < 4; ++r) {
            int oc = mt * 16 + lq * 4 + r;
            sc4[r] = scale2[oc];
            bi4[r] = bias2[oc];
        }
        #pragma unroll
        for (int nt = 0; nt < 2; ++nt) {
            int px = nt * 16 + l15;
            float g = nt ? g1 : g0;
            float xv[4];
            if (xr16) {
                // residual from bf16 NHWC copy: 4 consecutive oc = one ushort4
                size_t pix = (size_t)b * 65536 + (size_t)y * 256 + x0 + px;
                ushort4 u = *reinterpret_cast<const ushort4*>(xr16 + pix * 64 + mt * 16 + lq * 4);
                xv[0] = bf2f(u.x); xv[1] = bf2f(u.y); xv[2] = bf2f(u.z); xv[3] = bf2f(u.w);
            } else {
                #pragma unroll
                for (int r = 0; r < 4; ++r) {
                    int oc = mt * 16 + lq * 4 + r;
                    xv[r] = x[((size_t)(b * 64 + oc) * 256 + y) * 256 + x0 + px];
                }
            }
            #pragma unroll
            for (int r = 0; r < 4; ++r) {
                int oc = mt * 16 + lq * 4 + r;
                size_t base = ((size_t)(b * 64 + oc) * 256 + y) * 256 + x0;
                float v = acc[mt][nt][r] * sc4[r] + bi4[r];
                v = v * g + xv[r];
                out[base + px] = fmaxf(v, 0.f);
            }
        }
    }
}

extern "C" void kernel_launch(void* const* d_in, const int* in_sizes, int n_in,
                              void* d_out, int out_size, void* d_ws, size_t ws_size,
                              hipStream_t stream) {
    const float* x      = (const float*)d_in[0];
    const float* gate   = (const float*)d_in[1];
    const float* w1     = (const float*)d_in[2];
    const float* scale1 = (const float*)d_in[3];
    const float* bias1  = (const float*)d_in[4];
    const float* w2     = (const float*)d_in[5];
    const float* scale2 = (const float*)d_in[6];
    const float* bias2  = (const float*)d_in[7];
    float* out = (float*)d_out;

    char* ws = (char*)d_ws;
    const size_t HBYTES = 67108864;            // 64 MiB NHWC bf16 h
    const size_t NEED_BIG = 2 * HBYTES + 2 * 73728;

    // gmax (3x3 maxpool of gate) lives in `out` as scratch: consumed only by conv1,
    // then conv2 fully overwrites out (stream-ordered). Proven rounds 5-11.
    float* gmaxbuf = out;

    if (ws_size >= NEED_BIG) {
        unsigned short* hbuf = (unsigned short*)ws;
        unsigned short* xbf  = (unsigned short*)(ws + HBYTES);
        unsigned short* w1p  = (unsigned short*)(ws + 2 * HBYTES);
        unsigned short* w2p  = (unsigned short*)(ws + 2 * HBYTES + 73728);
        prep_all<<<2632, 1024, 0, stream>>>(w1, w2, x, gate, w1p, w2p, xbf, gmaxbuf);
        conv1_kernel<<<1024, 1024, 0, stream>>>(xbf, gmaxbuf, w1p, scale1, bias1, hbuf);
        conv2_kernel<<<1024, 1024, 0, stream>>>(hbuf, x, xbf, gate, w2p, scale2, bias2, out);
    } else {
        unsigned short* hbuf = (unsigned short*)ws;
        unsigned short* w1p  = (unsigned short*)(ws + HBYTES);
        unsigned short* w2p  = (unsigned short*)(ws + HBYTES + 73728);
        // fallback: only the 72 weight-prep blocks (no gmax/transpose sections launched)
        prep_all<<<72, 1024, 0, stream>>>(w1, w2, x, gate, w1p, w2p, nullptr, nullptr);
        conv1_fallback<<<1024, 1024, 0, stream>>>(x, gate, w1p, scale1, bias1, hbuf);
        conv2_kernel<<<1024, 1024, 0, stream>>>(hbuf, x, nullptr, gate, w2p, scale2, bias2, out);
    }
}